// Round 9
// baseline (231.870 us; speedup 1.0000x reference)
//
#include <hip/hip_runtime.h>
#include <hip/hip_fp16.h>

// QuantizedLinearWhisper: E2M1 block-32 fake-quant of x and W, then x_q @ W_q^T + bias.
// M=12000 (pad 12032=94*128), K=1280, N=5120. Outputs: out[12000][5120] f32, scale_w[5120][40] f32.
//
// R9 = R8 (128x256, BK=32, 8 waves 2x4, VGPR<=128 -> 2 blocks/CU, conflict-free
// (row>>1)&3 swizzle) + per-wave read/MFMA pipelining: fragment reads issued one
// phase ahead into parity ping-pong sets, counted lgkm(2), ONE barrier per K-tile,
// vmcnt(0) on a 1-tile staging lead. MFMA clusters run with reads in flight.

typedef _Float16 f16;
typedef _Float16 f16x8 __attribute__((ext_vector_type(8)));
typedef float f32x4 __attribute__((ext_vector_type(4)));

#define M_ROWS 12000
#define M_PAD  12032
#define N_COLS 5120
#define K_DIM  1280
#define KB     40
#define NTN    20          // N tiles of 256

#define BAR()   asm volatile("s_barrier" ::: "memory")
#define LGKM(N) asm volatile("s_waitcnt lgkmcnt(%0)" :: "i"(N) : "memory")
#define VMCNT(N) asm volatile("s_waitcnt vmcnt(%0)" :: "i"(N) : "memory")
#define GLDS(gp, lp) __builtin_amdgcn_global_load_lds( \
    (const __attribute__((address_space(1))) unsigned*)(gp), \
    (__attribute__((address_space(3))) unsigned*)(lp), 16, 0, 0)

// ---- E2M1 nearest-level (strict > boundaries, identical to reference) ----
__device__ __forceinline__ float e2m1_level(float a) {
    float lv;
    if (a > 2.5f)       lv = (a > 3.5f) ? ((a > 5.0f) ? 6.0f : 4.0f) : 3.0f;
    else if (a > 1.25f) lv = (a > 1.75f) ? 2.0f : 1.5f;
    else                lv = (a > 0.75f) ? 1.0f : ((a > 0.25f) ? 0.5f : 0.0f);
    return lv;
}

__global__ __launch_bounds__(256) void quant_x_kernel(const float* __restrict__ x,
                                                      f16* __restrict__ xq) {
    int t = blockIdx.x * blockDim.x + threadIdx.x;
    int row = t / 160;
    int c8  = t % 160;
    f16x8 o;
    if (row < M_ROWS) {
        const float* p = x + (size_t)row * K_DIM + c8 * 8;
        float v[8];
        *(float4*)&v[0] = *(const float4*)p;
        *(float4*)&v[4] = *(const float4*)(p + 4);
        float am = 0.0f;
        #pragma unroll
        for (int i = 0; i < 8; ++i) am = fmaxf(am, fabsf(v[i]));
        am = fmaxf(am, __shfl_xor(am, 1));
        am = fmaxf(am, __shfl_xor(am, 2));
        float scale = fmaxf(am / 6.0f, 1e-12f);
        #pragma unroll
        for (int i = 0; i < 8; ++i) {
            float tq = v[i] / scale;
            float q  = copysignf(e2m1_level(fabsf(tq)), tq) * scale;
            o[i] = (f16)q;
        }
    } else {
        #pragma unroll
        for (int i = 0; i < 8; ++i) o[i] = (f16)0.0f;
    }
    *(f16x8*)(xq + (size_t)row * K_DIM + c8 * 8) = o;
}

__global__ __launch_bounds__(256) void quant_w_kernel(const float* __restrict__ w,
                                                      f16* __restrict__ wq,
                                                      float* __restrict__ scale_out) {
    int t = blockIdx.x * blockDim.x + threadIdx.x;
    int row = t / 160;
    int c8  = t % 160;
    const float* p = w + (size_t)row * K_DIM + c8 * 8;
    float v[8];
    *(float4*)&v[0] = *(const float4*)p;
    *(float4*)&v[4] = *(const float4*)(p + 4);
    float am = 0.0f;
    #pragma unroll
    for (int i = 0; i < 8; ++i) am = fmaxf(am, fabsf(v[i]));
    am = fmaxf(am, __shfl_xor(am, 1));
    am = fmaxf(am, __shfl_xor(am, 2));
    float scale = fmaxf(am / 6.0f, 1e-12f);
    if ((t & 3) == 0) scale_out[row * KB + (c8 >> 2)] = scale;
    f16x8 o;
    #pragma unroll
    for (int i = 0; i < 8; ++i) {
        float tq = v[i] / scale;
        float q  = copysignf(e2m1_level(fabsf(tq)), tq) * scale;
        o[i] = (f16)q;
    }
    *(f16x8*)(wq + (size_t)row * K_DIM + c8 * 8) = o;
}

// ---- GEMM 128x256, BK=32 ----
// LDS (f16): per buffer A [128 rows][4 chunks 16B] = 4096, B [256][4] = 8192.
// Chunk c of row r stored at slot (c ^ ((r>>1)&3)); staging pre-swizzles the source.

__device__ __forceinline__ void stage_A32(const f16* __restrict__ g, f16* l, int tid) {
    int r = tid >> 2;
    int c = (tid & 3) ^ ((r >> 1) & 3);
    GLDS(g + (size_t)r * K_DIM + c * 8, l + (size_t)tid * 8);
}
__device__ __forceinline__ void stage_B32f(const f16* __restrict__ g, f16* l, int tid) {
    #pragma unroll
    for (int s = 0; s < 2; ++s) {
        int j   = s * 512 + tid;        // 1024 chunks
        int row = j >> 2;
        int c   = (j & 3) ^ ((row >> 1) & 3);
        GLDS(g + (size_t)row * K_DIM + c * 8, l + (size_t)j * 8);
    }
}

// One K-tile. X = buffer(t) (also overwrite target for t+2), Y = buffer(t+1).
// aF/blF: parity ping-pong fragment sets; set PAR holds tile t (read one phase ago).
// C1: issue bh(t) [2 ds]; lgkm(2); 8 MFMA (a*bl).
// C2: vmcnt(0) [Y staged]; lgkm(0) [bh read-before-overwrite]; BAR;
//     stage X<-t+2 [3 vm]; issue a/bl(t+1) from Y into set 1-PAR [6 ds];
//     8 MFMA (a*bh) with those reads in flight.
template<int PAR, bool STAGE, bool READNEXT>
__device__ __forceinline__ void ktile(const f16* Xa, const f16* Xb,
                                      f16* Wa, f16* Wb,
                                      const f16* Ya, const f16* Yb,
                                      const f16* gA2, const f16* gB2,
                                      f16x8 (&aF)[2][4], f16x8 (&blF)[2][2],
                                      f32x4 (&acc)[4][4],
                                      int tid, int arow0, int brow0, int swzc) {
    f16x8 bh[2];
    // ---- C1
    #pragma unroll
    for (int fn = 0; fn < 2; ++fn)
        bh[fn] = *(const f16x8*)&Xb[(brow0 + 32 + fn * 16) * 32 + swzc];
    LGKM(2);
    __builtin_amdgcn_s_setprio(1);
    #pragma unroll
    for (int fm = 0; fm < 4; ++fm)
        #pragma unroll
        for (int fn = 0; fn < 2; ++fn)
            acc[fm][fn] = __builtin_amdgcn_mfma_f32_16x16x32_f16(aF[PAR][fm], blF[PAR][fn], acc[fm][fn], 0, 0, 0);
    __builtin_amdgcn_s_setprio(0);

    // ---- C2
    VMCNT(0);
    LGKM(0);
    BAR();
    if (STAGE) { stage_A32(gA2, Wa, tid); stage_B32f(gB2, Wb, tid); }
    if (READNEXT) {
        #pragma unroll
        for (int fm = 0; fm < 4; ++fm)
            aF[1 - PAR][fm] = *(const f16x8*)&Ya[(arow0 + fm * 16) * 32 + swzc];
        #pragma unroll
        for (int fn = 0; fn < 2; ++fn)
            blF[1 - PAR][fn] = *(const f16x8*)&Yb[(brow0 + fn * 16) * 32 + swzc];
    }
    __builtin_amdgcn_s_setprio(1);
    #pragma unroll
    for (int fm = 0; fm < 4; ++fm)
        #pragma unroll
        for (int fn = 0; fn < 2; ++fn)
            acc[fm][fn + 2] = __builtin_amdgcn_mfma_f32_16x16x32_f16(aF[PAR][fm], bh[fn], acc[fm][fn + 2], 0, 0, 0);
    __builtin_amdgcn_s_setprio(0);
}

__global__ __launch_bounds__(512, 4) void gemm_kernel(const f16* __restrict__ A,
                                                      const f16* __restrict__ B,
                                                      const float* __restrict__ bias,
                                                      float* __restrict__ C) {
    __shared__ f16 sm[24576];              // 48 KiB: A0 B0 A1 B1
    f16* A0 = sm;
    f16* B0 = sm + 4096;
    f16* A1 = sm + 12288;
    f16* B1 = sm + 16384;

    int mt = blockIdx.x / NTN;             // 94 m-tiles of 128
    int nt = blockIdx.x % NTN;             // 20 n-tiles of 256

    int tid  = threadIdx.x;
    int lane = tid & 63;
    int wid  = tid >> 6;
    int wr   = wid >> 2;                   // 0..1  (M)
    int wc   = wid & 3;                    // 0..3  (N)
    int l15  = lane & 15;

    int swzc  = (((lane >> 4) ^ ((l15 >> 1) & 3)) << 3);
    int arow0 = wr * 64 + l15;
    int brow0 = wc * 64 + l15;

    const f16* gAb = A + (size_t)(mt * 128) * K_DIM;
    const f16* gBb = B + (size_t)(nt * 256) * K_DIM;

    f32x4 acc[4][4] = {};
    f16x8 aF[2][4], blF[2][2];

    // prologue: stage tile0 -> buf0 (3 vm), tile1 -> buf1 (3 vm); wait tile0; read frags(0)
    stage_A32(gAb,       A0, tid);
    stage_B32f(gBb,      B0, tid);
    stage_A32(gAb + 32,  A1, tid);
    stage_B32f(gBb + 32, B1, tid);
    VMCNT(3);
    BAR();
    #pragma unroll
    for (int fm = 0; fm < 4; ++fm)
        aF[0][fm] = *(const f16x8*)&A0[(arow0 + fm * 16) * 32 + swzc];
    #pragma unroll
    for (int fn = 0; fn < 2; ++fn)
        blF[0][fn] = *(const f16x8*)&B0[(brow0 + fn * 16) * 32 + swzc];

    // main: tiles 0..37 staged; t=38 reads next only; t=39 neither.
    for (int tt = 0; tt < 19; ++tt) {
        int t = 2 * tt;
        ktile<0, true, true>(A0, B0, A0, B0, A1, B1,
                             gAb + (t + 2) * 32, gBb + (t + 2) * 32,
                             aF, blF, acc, tid, arow0, brow0, swzc);
        ktile<1, true, true>(A1, B1, A1, B1, A0, B0,
                             gAb + (t + 3) * 32, gBb + (t + 3) * 32,
                             aF, blF, acc, tid, arow0, brow0, swzc);
    }
    ktile<0, false, true>(A0, B0, A0, B0, A1, B1, gAb, gBb,
                          aF, blF, acc, tid, arow0, brow0, swzc);   // t=38
    ktile<1, false, false>(A1, B1, A1, B1, A0, B0, gAb, gBb,
                           aF, blF, acc, tid, arow0, brow0, swzc);  // t=39

    // ---- epilogue: C = acc + bias.  C/D layout: col=lane&15, row=(lane>>4)*4+j
    int crow0 = mt * 128 + wr * 64;
    int ccol  = nt * 256 + wc * 64 + l15;
    float bz[4];
    #pragma unroll
    for (int fn = 0; fn < 4; ++fn) bz[fn] = bias[ccol + fn * 16];

    #pragma unroll
    for (int fm = 0; fm < 4; ++fm) {
        #pragma unroll
        for (int j = 0; j < 4; ++j) {
            int row = crow0 + fm * 16 + (lane >> 4) * 4 + j;
            if (row < M_ROWS) {
                float* cp = C + (size_t)row * N_COLS + ccol;
                #pragma unroll
                for (int fn = 0; fn < 4; ++fn)
                    cp[fn * 16] = acc[fm][fn][j] + bz[fn];
            }
        }
    }
}

extern "C" void kernel_launch(void* const* d_in, const int* in_sizes, int n_in,
                              void* d_out, int out_size, void* d_ws, size_t ws_size,
                              hipStream_t stream) {
    const float* x      = (const float*)d_in[0];
    const float* weight = (const float*)d_in[1];
    const float* bias   = (const float*)d_in[2];
    float* out     = (float*)d_out;
    float* scale_w = (float*)d_out + (size_t)M_ROWS * N_COLS;

    f16* xq = (f16*)d_ws;
    f16* wq = (f16*)((char*)d_ws + (size_t)M_PAD * K_DIM * sizeof(f16));

    {
        int threads = M_PAD * (K_DIM / 8);
        quant_x_kernel<<<threads / 256, 256, 0, stream>>>(x, xq);
    }
    {
        int threads = N_COLS * (K_DIM / 8);
        quant_w_kernel<<<threads / 256, 256, 0, stream>>>(weight, wq, scale_w);
    }
    {
        int grid = (M_PAD / 128) * (N_COLS / 256);   // 94 * 20 = 1880
        gemm_kernel<<<grid, 512, 0, stream>>>(xq, wq, bias, out);
    }
}